// Round 1
// baseline (2450.040 us; speedup 1.0000x reference)
//
#include <hip/hip_runtime.h>
#include <stdint.h>

#define F_IN 512
#define HDIM 128
#define CDIM 16
#define KHOPS 10

typedef __bf16 bf16x8 __attribute__((ext_vector_type(8)));
typedef float f32x4 __attribute__((ext_vector_type(4)));

__device__ __forceinline__ unsigned short f2bf(float f) {
    unsigned int u = __float_as_uint(f);
    u += 0x7FFFu + ((u >> 16) & 1u);
    return (unsigned short)(u >> 16);
}
__device__ __forceinline__ float bf2f(unsigned short s) {
    return __uint_as_float(((unsigned int)s) << 16);
}

// ---------------- CSC build ----------------

__global__ void k_count(const int* __restrict__ eidx, int* __restrict__ cnt, int E) {
    int e = blockIdx.x * 256 + threadIdx.x;
    if (e < E) atomicAdd(&cnt[eidx[E + e]], 1);
}

__global__ void k_dis(const int* __restrict__ cnt, float* __restrict__ dis, int N) {
    int v = blockIdx.x * 256 + threadIdx.x;
    if (v < N) dis[v] = rsqrtf((float)(cnt[v] + 1));
}

// 1024 elements per block, 256 threads x 4
__global__ void k_scan1(const int* __restrict__ cnt, int* __restrict__ offs,
                        int* __restrict__ partials, int N) {
    __shared__ int sh[256];
    int t = threadIdx.x;
    int base = blockIdx.x * 1024 + t * 4;
    int v0 = (base + 0 < N) ? cnt[base + 0] : 0;
    int v1 = (base + 1 < N) ? cnt[base + 1] : 0;
    int v2 = (base + 2 < N) ? cnt[base + 2] : 0;
    int v3 = (base + 3 < N) ? cnt[base + 3] : 0;
    int s = v0 + v1 + v2 + v3;
    sh[t] = s;
    __syncthreads();
    for (int d = 1; d < 256; d <<= 1) {
        int x = (t >= d) ? sh[t - d] : 0;
        __syncthreads();
        sh[t] += x;
        __syncthreads();
    }
    int excl = sh[t] - s;
    if (base + 0 < N) offs[base + 0] = excl;
    excl += v0;
    if (base + 1 < N) offs[base + 1] = excl;
    excl += v1;
    if (base + 2 < N) offs[base + 2] = excl;
    excl += v2;
    if (base + 3 < N) offs[base + 3] = excl;
    if (t == 255) partials[blockIdx.x] = sh[255];
}

// exclusive scan of up to 1024 partials, in place, single block
__global__ void k_scan2(int* __restrict__ partials, int nblk) {
    __shared__ int sh[256];
    int t = threadIdx.x;
    int i0 = t * 4;
    int v0 = (i0 + 0 < nblk) ? partials[i0 + 0] : 0;
    int v1 = (i0 + 1 < nblk) ? partials[i0 + 1] : 0;
    int v2 = (i0 + 2 < nblk) ? partials[i0 + 2] : 0;
    int v3 = (i0 + 3 < nblk) ? partials[i0 + 3] : 0;
    int s = v0 + v1 + v2 + v3;
    sh[t] = s;
    __syncthreads();
    for (int d = 1; d < 256; d <<= 1) {
        int x = (t >= d) ? sh[t - d] : 0;
        __syncthreads();
        sh[t] += x;
        __syncthreads();
    }
    int excl = sh[t] - s;
    if (i0 + 0 < nblk) partials[i0 + 0] = excl;
    excl += v0;
    if (i0 + 1 < nblk) partials[i0 + 1] = excl;
    excl += v1;
    if (i0 + 2 < nblk) partials[i0 + 2] = excl;
    excl += v2;
    if (i0 + 3 < nblk) partials[i0 + 3] = excl;
}

__global__ void k_scan3(int* __restrict__ offs, const int* __restrict__ partials, int N) {
    int i = blockIdx.x * 256 + threadIdx.x;
    if (i < N) offs[i] += partials[i >> 10];
}

__global__ void k_bucket(const int* __restrict__ eidx, const float* __restrict__ dis,
                         const int* __restrict__ offs, int* __restrict__ cursor,
                         uint2* __restrict__ srcnrm, int E) {
    int e = blockIdx.x * 256 + threadIdx.x;
    if (e >= E) return;
    int r = eidx[e];
    int c = eidx[E + e];
    int pos = offs[c] + atomicAdd(&cursor[c], 1);
    uint2 u;
    u.x = (unsigned)r;
    u.y = __float_as_uint(dis[r] * dis[c]);
    srcnrm[pos] = u;
}

// ---------------- fused GEMM: h1 = relu(x@W1+b1); h2 = h1@W2+b2 ----------------
// grid (ceil(N/128), 2), 256 threads. blockIdx.y = branch (0=l, 1=g)

__global__ __launch_bounds__(256) void k_gemm(
    const float* __restrict__ x,
    const float* __restrict__ W1l, const float* __restrict__ b1l,
    const float* __restrict__ W2l, const float* __restrict__ b2l, const float* __restrict__ tl,
    const float* __restrict__ W1g, const float* __restrict__ b1g,
    const float* __restrict__ W2g, const float* __restrict__ b2g, const float* __restrict__ tg,
    float* __restrict__ h1l, float* __restrict__ h1g,
    float* __restrict__ xc0, float* __restrict__ hid, int nNode)
{
    const int br = blockIdx.y;
    const float* W1 = br ? W1g : W1l;
    const float* B1 = br ? b1g : b1l;
    const float* W2 = br ? W2g : W2l;
    const float* B2 = br ? b2g : b2l;
    const float* tp = br ? tg : tl;
    float* h1 = br ? h1g : h1l;

    __shared__ __align__(16) unsigned short As[128 * 40];   // [m][k] pad to 40
    __shared__ __align__(16) unsigned short Bs[128 * 40];   // [n][k] pad to 40
    __shared__ __align__(16) unsigned short Hs[128 * 136];  // h1 stash bf16, [m][k] pad 136

    const int t = threadIdx.x;
    const int lane = t & 63;
    const int w = t >> 6;
    const int row0 = blockIdx.x * 128;

    f32x4 acc[2][8];
    for (int i = 0; i < 2; i++)
        for (int j = 0; j < 8; j++)
            acc[i][j] = f32x4{0.f, 0.f, 0.f, 0.f};

    const int m16 = lane & 15;
    const int q = lane >> 4;

    for (int k0 = 0; k0 < F_IN; k0 += 32) {
        // stage A: x tile 128x32 f32 -> bf16
        for (int i = 0; i < 4; i++) {
            int linear = i * 256 + t;
            int r = linear >> 3;
            int c4 = (linear & 7) * 4;
            float4 v = make_float4(0.f, 0.f, 0.f, 0.f);
            if (row0 + r < nNode)
                v = *reinterpret_cast<const float4*>(&x[(size_t)(row0 + r) * F_IN + k0 + c4]);
            uint2 p;
            p.x = (unsigned)f2bf(v.x) | ((unsigned)f2bf(v.y) << 16);
            p.y = (unsigned)f2bf(v.z) | ((unsigned)f2bf(v.w) << 16);
            *reinterpret_cast<uint2*>(&As[r * 40 + c4]) = p;
        }
        // stage B: W1 tile 32x128 transposed -> Bs[n][k]
        {
            int n = t >> 1;
            int ks = (t & 1) * 16;
            unsigned short tmp[16];
            for (int j = 0; j < 16; j++)
                tmp[j] = f2bf(W1[(size_t)(k0 + ks + j) * HDIM + n]);
            uint4* dst = reinterpret_cast<uint4*>(&Bs[n * 40 + ks]);
            dst[0] = *reinterpret_cast<uint4*>(&tmp[0]);
            dst[1] = *reinterpret_cast<uint4*>(&tmp[8]);
        }
        __syncthreads();

        bf16x8 af[2];
        for (int ms = 0; ms < 2; ms++) {
            const uint4* pa = reinterpret_cast<const uint4*>(&As[(w * 32 + ms * 16 + m16) * 40 + q * 8]);
            af[ms] = __builtin_bit_cast(bf16x8, *pa);
        }
        for (int ns = 0; ns < 8; ns++) {
            const uint4* pb = reinterpret_cast<const uint4*>(&Bs[(ns * 16 + m16) * 40 + q * 8]);
            bf16x8 bfrag = __builtin_bit_cast(bf16x8, *pb);
            for (int ms = 0; ms < 2; ms++)
                acc[ms][ns] = __builtin_amdgcn_mfma_f32_16x16x32_bf16(af[ms], bfrag, acc[ms][ns], 0, 0, 0);
        }
        __syncthreads();
    }

    // epilogue 1: h1 = relu(acc + b1); write global + stash bf16 in LDS
    for (int ms = 0; ms < 2; ms++) {
        for (int ns = 0; ns < 8; ns++) {
            int n = ns * 16 + m16;
            float bias = B1[n];
            for (int r = 0; r < 4; r++) {
                int m = w * 32 + ms * 16 + q * 4 + r;
                float v = acc[ms][ns][r] + bias;
                v = v > 0.f ? v : 0.f;
                Hs[m * 136 + n] = f2bf(v);
                int node = row0 + m;
                if (node < nNode) h1[(size_t)node * HDIM + n] = v;
            }
        }
    }
    __syncthreads();

    // epilogue 2: h2 = h1 @ W2 + b2 ; write xc0 and hid (interleaved [N][32])
    {
        int r = t >> 1;
        int cg = (t & 1) * 8;
        float a8[8];
        for (int j = 0; j < 8; j++) a8[j] = B2[cg + j];
        for (int kb = 0; kb < 16; kb++) {
            uint4 hh = *reinterpret_cast<const uint4*>(&Hs[r * 136 + kb * 8]);
            unsigned short hs[8];
            *reinterpret_cast<uint4*>(hs) = hh;
            for (int j = 0; j < 8; j++) {
                float hv = bf2f(hs[j]);
                const float* w2r = &W2[(size_t)(kb * 8 + j) * CDIM + cg];
                for (int qq = 0; qq < 8; qq++) a8[qq] += hv * w2r[qq];
            }
        }
        int node = row0 + r;
        if (node < nNode) {
            float t0 = tp[0];
            for (int j = 0; j < 8; j++) {
                size_t idx = (size_t)node * 32 + (size_t)br * 16 + cg + j;
                xc0[idx] = a8[j];
                hid[idx] = t0 * a8[j];
            }
        }
    }
}

// ---------------- propagation hop (both branches jointly, [N][32]) ----------------
// block = 256 threads = 8 nodes x 32 channels

__global__ void k_hop(const float* __restrict__ xin, float* __restrict__ xout,
                      float* __restrict__ hid, const uint2* __restrict__ srcnrm,
                      const int* __restrict__ offs, const int* __restrict__ cnt,
                      const float* __restrict__ dis,
                      const float* __restrict__ tl, const float* __restrict__ tg,
                      int hop, int N)
{
    int t = threadIdx.x;
    int v = blockIdx.x * 8 + (t >> 5);
    int c = t & 31;
    if (v >= N) return;
    int off = offs[v];
    int m = cnt[v];
    float d = dis[v];
    float acc = d * d * xin[(size_t)v * 32 + c];
    for (int i = 0; i < m; i++) {
        uint2 u = srcnrm[off + i];
        acc += __uint_as_float(u.y) * xin[(size_t)u.x * 32 + c];
    }
    size_t idx = (size_t)v * 32 + c;
    xout[idx] = acc;
    float gamma = (c < 16 ? tl : tg)[hop];
    hid[idx] += gamma * acc;
}

// ---------------- final: split hid, log_softmax ----------------

__global__ void k_final(const float* __restrict__ hid,
                        float* __restrict__ h2l, float* __restrict__ pl,
                        float* __restrict__ h2g, float* __restrict__ pg, int N)
{
    int t = threadIdx.x;
    int v = blockIdx.x * 128 + (t >> 1);
    int br = t & 1;
    if (v >= N) return;
    float xv[16];
    const float* src = &hid[(size_t)v * 32 + (size_t)br * 16];
    for (int j = 0; j < 16; j += 4)
        *reinterpret_cast<float4*>(&xv[j]) = *reinterpret_cast<const float4*>(&src[j]);
    float mx = xv[0];
    for (int j = 1; j < 16; j++) mx = fmaxf(mx, xv[j]);
    float s = 0.f;
    for (int j = 0; j < 16; j++) s += __expf(xv[j] - mx);
    float lse = mx + __logf(s);
    float* h2 = br ? h2g : h2l;
    float* pp = br ? pg : pl;
    for (int j = 0; j < 16; j++) {
        h2[(size_t)v * 16 + j] = xv[j];
        pp[(size_t)v * 16 + j] = xv[j] - lse;
    }
}

// ---------------- launch ----------------

extern "C" void kernel_launch(void* const* d_in, const int* in_sizes, int n_in,
                              void* d_out, int out_size, void* d_ws, size_t ws_size,
                              hipStream_t stream)
{
    const float* x   = (const float*)d_in[0];
    const int*   eidx= (const int*)d_in[1];
    const float* W1l = (const float*)d_in[2];
    const float* b1l = (const float*)d_in[3];
    const float* W2l = (const float*)d_in[4];
    const float* b2l = (const float*)d_in[5];
    const float* tl  = (const float*)d_in[6];
    const float* W1g = (const float*)d_in[7];
    const float* b1g = (const float*)d_in[8];
    const float* W2g = (const float*)d_in[9];
    const float* b2g = (const float*)d_in[10];
    const float* tg  = (const float*)d_in[11];

    const int N = in_sizes[0] / F_IN;
    const int E = in_sizes[1] / 2;

    float* out = (float*)d_out;
    float* h1l = out;
    float* h2l = h1l + (size_t)N * HDIM;
    float* pl  = h2l + (size_t)N * CDIM;
    float* h1g = pl  + (size_t)N * CDIM;
    float* h2g = h1g + (size_t)N * HDIM;
    float* pg  = h2g + (size_t)N * CDIM;

    char* ws = (char*)d_ws;
    auto alloc = [&](size_t bytes) -> char* {
        char* p = ws;
        ws += (bytes + 1023) & ~(size_t)1023;
        return p;
    };
    int*   cnt      = (int*)alloc((size_t)N * 4);
    int*   offs     = (int*)alloc((size_t)N * 4);
    int*   cursor   = (int*)alloc((size_t)N * 4);
    float* dis      = (float*)alloc((size_t)N * 4);
    int*   partials = (int*)alloc(4096);
    uint2* srcnrm   = (uint2*)alloc((size_t)E * 8);
    float* xcA      = (float*)alloc((size_t)N * 32 * 4);
    float* xcB      = (float*)alloc((size_t)N * 32 * 4);
    float* hid      = (float*)alloc((size_t)N * 32 * 4);

    hipMemsetAsync(cnt, 0, (size_t)N * 4, stream);
    hipMemsetAsync(cursor, 0, (size_t)N * 4, stream);

    int gE = (E + 255) / 256;
    int gN = (N + 255) / 256;
    int nblk = (N + 1023) / 1024;

    k_count<<<gE, 256, 0, stream>>>(eidx, cnt, E);
    k_dis<<<gN, 256, 0, stream>>>(cnt, dis, N);
    k_scan1<<<nblk, 256, 0, stream>>>(cnt, offs, partials, N);
    k_scan2<<<1, 256, 0, stream>>>(partials, nblk);
    k_scan3<<<gN, 256, 0, stream>>>(offs, partials, N);
    k_bucket<<<gE, 256, 0, stream>>>(eidx, dis, offs, cursor, srcnrm, E);

    dim3 gg((N + 127) / 128, 2);
    k_gemm<<<gg, 256, 0, stream>>>(x, W1l, b1l, W2l, b2l, tl,
                                   W1g, b1g, W2g, b2g, tg,
                                   h1l, h1g, xcA, hid, N);

    int gh = (N + 7) / 8;
    float* a = xcA;
    float* b = xcB;
    for (int k = 1; k <= KHOPS; k++) {
        k_hop<<<gh, 256, 0, stream>>>(a, b, hid, srcnrm, offs, cnt, dis, tl, tg, k, N);
        float* tmp = a; a = b; b = tmp;
    }
    k_final<<<(N + 127) / 128, 256, 0, stream>>>(hid, h2l, pl, h2g, pg, N);
}

// Round 2
// 1521.736 us; speedup vs baseline: 1.6100x; 1.6100x over previous
//
#include <hip/hip_runtime.h>
#include <stdint.h>

#define F_IN 512
#define HDIM 128
#define CDIM 16
#define KHOPS 10

typedef __bf16 bf16x8 __attribute__((ext_vector_type(8)));
typedef float f32x4 __attribute__((ext_vector_type(4)));

__device__ __forceinline__ unsigned short f2bf(float f) {
    unsigned int u = __float_as_uint(f);
    u += 0x7FFFu + ((u >> 16) & 1u);
    return (unsigned short)(u >> 16);
}
__device__ __forceinline__ float bf2f(unsigned short s) {
    return __uint_as_float(((unsigned int)s) << 16);
}

// ---------------- CSC build ----------------

__global__ void k_count(const int* __restrict__ eidx, int* __restrict__ cnt, int E) {
    int e = blockIdx.x * 256 + threadIdx.x;
    if (e < E) atomicAdd(&cnt[eidx[E + e]], 1);
}

__global__ void k_dis(const int* __restrict__ cnt, float* __restrict__ dis, int N) {
    int v = blockIdx.x * 256 + threadIdx.x;
    if (v < N) dis[v] = rsqrtf((float)(cnt[v] + 1));
}

// 1024 elements per block, 256 threads x 4
__global__ void k_scan1(const int* __restrict__ cnt, int* __restrict__ offs,
                        int* __restrict__ partials, int N) {
    __shared__ int sh[256];
    int t = threadIdx.x;
    int base = blockIdx.x * 1024 + t * 4;
    int v0 = (base + 0 < N) ? cnt[base + 0] : 0;
    int v1 = (base + 1 < N) ? cnt[base + 1] : 0;
    int v2 = (base + 2 < N) ? cnt[base + 2] : 0;
    int v3 = (base + 3 < N) ? cnt[base + 3] : 0;
    int s = v0 + v1 + v2 + v3;
    sh[t] = s;
    __syncthreads();
    for (int d = 1; d < 256; d <<= 1) {
        int x = (t >= d) ? sh[t - d] : 0;
        __syncthreads();
        sh[t] += x;
        __syncthreads();
    }
    int excl = sh[t] - s;
    if (base + 0 < N) offs[base + 0] = excl;
    excl += v0;
    if (base + 1 < N) offs[base + 1] = excl;
    excl += v1;
    if (base + 2 < N) offs[base + 2] = excl;
    excl += v2;
    if (base + 3 < N) offs[base + 3] = excl;
    if (t == 255) partials[blockIdx.x] = sh[255];
}

__global__ void k_scan2(int* __restrict__ partials, int nblk) {
    __shared__ int sh[256];
    int t = threadIdx.x;
    int i0 = t * 4;
    int v0 = (i0 + 0 < nblk) ? partials[i0 + 0] : 0;
    int v1 = (i0 + 1 < nblk) ? partials[i0 + 1] : 0;
    int v2 = (i0 + 2 < nblk) ? partials[i0 + 2] : 0;
    int v3 = (i0 + 3 < nblk) ? partials[i0 + 3] : 0;
    int s = v0 + v1 + v2 + v3;
    sh[t] = s;
    __syncthreads();
    for (int d = 1; d < 256; d <<= 1) {
        int x = (t >= d) ? sh[t - d] : 0;
        __syncthreads();
        sh[t] += x;
        __syncthreads();
    }
    int excl = sh[t] - s;
    if (i0 + 0 < nblk) partials[i0 + 0] = excl;
    excl += v0;
    if (i0 + 1 < nblk) partials[i0 + 1] = excl;
    excl += v1;
    if (i0 + 2 < nblk) partials[i0 + 2] = excl;
    excl += v2;
    if (i0 + 3 < nblk) partials[i0 + 3] = excl;
}

__global__ void k_scan3(int* __restrict__ offs, const int* __restrict__ partials, int N) {
    int i = blockIdx.x * 256 + threadIdx.x;
    if (i < N) offs[i] += partials[i >> 10];
}

__global__ void k_bucket(const int* __restrict__ eidx, const float* __restrict__ dis,
                         const int* __restrict__ offs, int* __restrict__ cursor,
                         uint2* __restrict__ srcnrm, int E) {
    int e = blockIdx.x * 256 + threadIdx.x;
    if (e >= E) return;
    int r = eidx[e];
    int c = eidx[E + e];
    int pos = offs[c] + atomicAdd(&cursor[c], 1);
    uint2 u;
    u.x = (unsigned)r;
    u.y = __float_as_uint(dis[r] * dis[c]);
    srcnrm[pos] = u;
}

// ---------------- W1 transpose+convert: [512][128] f32 -> [128][512] bf16 ----------------
// grid (32, 2): 8192 threads per branch, each does 8 k for one n

__global__ void k_w1t(const float* __restrict__ W1l, const float* __restrict__ W1g,
                      unsigned short* __restrict__ W1Tl, unsigned short* __restrict__ W1Tg) {
    const float* W1 = blockIdx.y ? W1g : W1l;
    unsigned short* W1T = blockIdx.y ? W1Tg : W1Tl;
    int idx = blockIdx.x * 256 + threadIdx.x;   // 0..8191
    int n = idx >> 6;                           // 0..127
    int k0 = (idx & 63) * 8;                    // 0..504
    unsigned short tmp[8];
    for (int j = 0; j < 8; j++)
        tmp[j] = f2bf(W1[(size_t)(k0 + j) * HDIM + n]);
    *reinterpret_cast<uint4*>(&W1T[(size_t)n * F_IN + k0]) = *reinterpret_cast<uint4*>(tmp);
}

// ---------------- fused GEMM: h1 = relu(x@W1+b1); h2 = h1@W2+b2 ----------------
// grid (ceil(N/128), 2), 256 threads. blockIdx.y = branch (0=l, 1=g)
// LDS: union { As[128][72] bf16 (K-loop) ; Hs[128][136] bf16 (epilogue) } = 34816 B

__global__ __launch_bounds__(256, 4) void k_gemm(
    const float* __restrict__ x,
    const unsigned short* __restrict__ W1Tl, const float* __restrict__ b1l,
    const float* __restrict__ W2l, const float* __restrict__ b2l, const float* __restrict__ tl,
    const unsigned short* __restrict__ W1Tg, const float* __restrict__ b1g,
    const float* __restrict__ W2g, const float* __restrict__ b2g, const float* __restrict__ tg,
    float* __restrict__ h1l, float* __restrict__ h1g,
    float* __restrict__ xc0, float* __restrict__ hid, int nNode)
{
    const int br = blockIdx.y;
    const unsigned short* w1t = br ? W1Tg : W1Tl;
    const float* B1 = br ? b1g : b1l;
    const float* W2 = br ? W2g : W2l;
    const float* B2 = br ? b2g : b2l;
    const float* tp = br ? tg : tl;
    float* h1 = br ? h1g : h1l;

    __shared__ __align__(16) unsigned short sm[17408];   // 34816 B
    unsigned short* As = sm;    // [128][72], valid during K loop
    unsigned short* Hs = sm;    // [128][136], valid after K loop

    const int t = threadIdx.x;
    const int lane = t & 63;
    const int w = t >> 6;
    const int row0 = blockIdx.x * 128;

    f32x4 acc[2][8];
    for (int i = 0; i < 2; i++)
        for (int j = 0; j < 8; j++)
            acc[i][j] = f32x4{0.f, 0.f, 0.f, 0.f};

    const int m16 = lane & 15;
    const int q = lane >> 4;

    for (int k0 = 0; k0 < F_IN; k0 += 64) {
        // stage A: x tile 128x64 f32 -> bf16. 2048 float4 / 256 threads = 8 each.
        // threads 0..15 cover row r contiguously (16B each) -> coalesced.
        #pragma unroll
        for (int i = 0; i < 8; i++) {
            int linear = i * 256 + t;
            int r = linear >> 4;
            int c4 = (linear & 15) * 4;
            float4 v = make_float4(0.f, 0.f, 0.f, 0.f);
            if (row0 + r < nNode)
                v = *reinterpret_cast<const float4*>(&x[(size_t)(row0 + r) * F_IN + k0 + c4]);
            uint2 p;
            p.x = (unsigned)f2bf(v.x) | ((unsigned)f2bf(v.y) << 16);
            p.y = (unsigned)f2bf(v.z) | ((unsigned)f2bf(v.w) << 16);
            *reinterpret_cast<uint2*>(&As[r * 72 + c4]) = p;
        }
        __syncthreads();

        #pragma unroll
        for (int ksub = 0; ksub < 2; ksub++) {
            // B frags straight from L2-resident W1T (bf16 [n][k])
            bf16x8 bf[8];
            #pragma unroll
            for (int ns = 0; ns < 8; ns++) {
                int n = ns * 16 + m16;
                const uint4* pb = reinterpret_cast<const uint4*>(
                    &w1t[(size_t)n * F_IN + k0 + ksub * 32 + q * 8]);
                bf[ns] = __builtin_bit_cast(bf16x8, *pb);
            }
            bf16x8 af[2];
            #pragma unroll
            for (int ms = 0; ms < 2; ms++) {
                const uint4* pa = reinterpret_cast<const uint4*>(
                    &As[(w * 32 + ms * 16 + m16) * 72 + ksub * 32 + q * 8]);
                af[ms] = __builtin_bit_cast(bf16x8, *pa);
            }
            #pragma unroll
            for (int ns = 0; ns < 8; ns++)
                #pragma unroll
                for (int ms = 0; ms < 2; ms++)
                    acc[ms][ns] = __builtin_amdgcn_mfma_f32_16x16x32_bf16(af[ms], bf[ns], acc[ms][ns], 0, 0, 0);
        }
        __syncthreads();
    }

    // epilogue 1: h1 = relu(acc + b1); write global + stash bf16 in LDS (reuses As space)
    #pragma unroll
    for (int ms = 0; ms < 2; ms++) {
        #pragma unroll
        for (int ns = 0; ns < 8; ns++) {
            int n = ns * 16 + m16;
            float bias = B1[n];
            #pragma unroll
            for (int r = 0; r < 4; r++) {
                int m = w * 32 + ms * 16 + q * 4 + r;
                float v = acc[ms][ns][r] + bias;
                v = v > 0.f ? v : 0.f;
                Hs[m * 136 + n] = f2bf(v);
                int node = row0 + m;
                if (node < nNode) h1[(size_t)node * HDIM + n] = v;
            }
        }
    }
    __syncthreads();

    // epilogue 2: h2 = h1 @ W2 + b2 ; write xc0 and hid (interleaved [N][32])
    {
        int r = t >> 1;
        int cg = (t & 1) * 8;
        float a8[8];
        for (int j = 0; j < 8; j++) a8[j] = B2[cg + j];
        for (int kb = 0; kb < 16; kb++) {
            uint4 hh = *reinterpret_cast<const uint4*>(&Hs[r * 136 + kb * 8]);
            unsigned short hs[8];
            *reinterpret_cast<uint4*>(hs) = hh;
            for (int j = 0; j < 8; j++) {
                float hv = bf2f(hs[j]);
                const float* w2r = &W2[(size_t)(kb * 8 + j) * CDIM + cg];
                for (int qq = 0; qq < 8; qq++) a8[qq] += hv * w2r[qq];
            }
        }
        int node = row0 + r;
        if (node < nNode) {
            float t0 = tp[0];
            for (int j = 0; j < 8; j++) {
                size_t idx = (size_t)node * 32 + (size_t)br * 16 + cg + j;
                xc0[idx] = a8[j];
                hid[idx] = t0 * a8[j];
            }
        }
    }
}

// ---------------- propagation hop (both branches jointly, [N][32]) ----------------
// block = 256 threads = 8 nodes x 32 channels; edge loop unrolled x8 for gather ILP

__global__ __launch_bounds__(256) void k_hop(
    const float* __restrict__ xin, float* __restrict__ xout,
    float* __restrict__ hid, const uint2* __restrict__ srcnrm,
    const int* __restrict__ offs, const int* __restrict__ cnt,
    const float* __restrict__ dis,
    const float* __restrict__ tl, const float* __restrict__ tg,
    int hop, int N)
{
    int t = threadIdx.x;
    int v = blockIdx.x * 8 + (t >> 5);
    int c = t & 31;
    if (v >= N) return;
    int off = offs[v];
    int m = cnt[v];
    float d = dis[v];
    float acc = d * d * xin[(size_t)v * 32 + c];
    const uint2* ep = srcnrm + off;
    int i = 0;
    for (; i + 8 <= m; i += 8) {
        uint2 u[8];
        #pragma unroll
        for (int j = 0; j < 8; j++) u[j] = ep[i + j];
        float xs[8];
        #pragma unroll
        for (int j = 0; j < 8; j++) xs[j] = xin[(size_t)u[j].x * 32 + c];
        #pragma unroll
        for (int j = 0; j < 8; j++) acc = fmaf(__uint_as_float(u[j].y), xs[j], acc);
    }
    for (; i < m; i++) {
        uint2 u = ep[i];
        acc = fmaf(__uint_as_float(u.y), xin[(size_t)u.x * 32 + c], acc);
    }
    size_t idx = (size_t)v * 32 + c;
    xout[idx] = acc;
    float gamma = (c < 16 ? tl : tg)[hop];
    hid[idx] += gamma * acc;
}

// ---------------- final: split hid, log_softmax ----------------

__global__ void k_final(const float* __restrict__ hid,
                        float* __restrict__ h2l, float* __restrict__ pl,
                        float* __restrict__ h2g, float* __restrict__ pg, int N)
{
    int t = threadIdx.x;
    int v = blockIdx.x * 128 + (t >> 1);
    int br = t & 1;
    if (v >= N) return;
    float xv[16];
    const float* src = &hid[(size_t)v * 32 + (size_t)br * 16];
    for (int j = 0; j < 16; j += 4)
        *reinterpret_cast<float4*>(&xv[j]) = *reinterpret_cast<const float4*>(&src[j]);
    float mx = xv[0];
    for (int j = 1; j < 16; j++) mx = fmaxf(mx, xv[j]);
    float s = 0.f;
    for (int j = 0; j < 16; j++) s += __expf(xv[j] - mx);
    float lse = mx + __logf(s);
    float* h2 = br ? h2g : h2l;
    float* pp = br ? pg : pl;
    for (int j = 0; j < 16; j++) {
        h2[(size_t)v * 16 + j] = xv[j];
        pp[(size_t)v * 16 + j] = xv[j] - lse;
    }
}

// ---------------- launch ----------------

extern "C" void kernel_launch(void* const* d_in, const int* in_sizes, int n_in,
                              void* d_out, int out_size, void* d_ws, size_t ws_size,
                              hipStream_t stream)
{
    const float* x   = (const float*)d_in[0];
    const int*   eidx= (const int*)d_in[1];
    const float* W1l = (const float*)d_in[2];
    const float* b1l = (const float*)d_in[3];
    const float* W2l = (const float*)d_in[4];
    const float* b2l = (const float*)d_in[5];
    const float* tl  = (const float*)d_in[6];
    const float* W1g = (const float*)d_in[7];
    const float* b1g = (const float*)d_in[8];
    const float* W2g = (const float*)d_in[9];
    const float* b2g = (const float*)d_in[10];
    const float* tg  = (const float*)d_in[11];

    const int N = in_sizes[0] / F_IN;
    const int E = in_sizes[1] / 2;

    float* out = (float*)d_out;
    float* h1l = out;
    float* h2l = h1l + (size_t)N * HDIM;
    float* pl  = h2l + (size_t)N * CDIM;
    float* h1g = pl  + (size_t)N * CDIM;
    float* h2g = h1g + (size_t)N * HDIM;
    float* pg  = h2g + (size_t)N * CDIM;

    char* ws = (char*)d_ws;
    auto alloc = [&](size_t bytes) -> char* {
        char* p = ws;
        ws += (bytes + 1023) & ~(size_t)1023;
        return p;
    };
    int*   cnt      = (int*)alloc((size_t)N * 4);
    int*   offs     = (int*)alloc((size_t)N * 4);
    int*   cursor   = (int*)alloc((size_t)N * 4);
    float* dis      = (float*)alloc((size_t)N * 4);
    int*   partials = (int*)alloc(4096);
    uint2* srcnrm   = (uint2*)alloc((size_t)E * 8);
    float* xcA      = (float*)alloc((size_t)N * 32 * 4);
    float* xcB      = (float*)alloc((size_t)N * 32 * 4);
    float* hid      = (float*)alloc((size_t)N * 32 * 4);
    unsigned short* W1Tl = (unsigned short*)alloc((size_t)HDIM * F_IN * 2);
    unsigned short* W1Tg = (unsigned short*)alloc((size_t)HDIM * F_IN * 2);

    hipMemsetAsync(cnt, 0, (size_t)N * 4, stream);
    hipMemsetAsync(cursor, 0, (size_t)N * 4, stream);

    int gE = (E + 255) / 256;
    int gN = (N + 255) / 256;
    int nblk = (N + 1023) / 1024;

    k_count<<<gE, 256, 0, stream>>>(eidx, cnt, E);
    k_dis<<<gN, 256, 0, stream>>>(cnt, dis, N);
    k_scan1<<<nblk, 256, 0, stream>>>(cnt, offs, partials, N);
    k_scan2<<<1, 256, 0, stream>>>(partials, nblk);
    k_scan3<<<gN, 256, 0, stream>>>(offs, partials, N);
    k_bucket<<<gE, 256, 0, stream>>>(eidx, dis, offs, cursor, srcnrm, E);

    dim3 gw(32, 2);
    k_w1t<<<gw, 256, 0, stream>>>(W1l, W1g, W1Tl, W1Tg);

    dim3 gg((N + 127) / 128, 2);
    k_gemm<<<gg, 256, 0, stream>>>(x, W1Tl, b1l, W2l, b2l, tl,
                                   W1Tg, b1g, W2g, b2g, tg,
                                   h1l, h1g, xcA, hid, N);

    int gh = (N + 7) / 8;
    float* a = xcA;
    float* b = xcB;
    for (int k = 1; k <= KHOPS; k++) {
        k_hop<<<gh, 256, 0, stream>>>(a, b, hid, srcnrm, offs, cnt, dis, tl, tg, k, N);
        float* tmp = a; a = b; b = tmp;
    }
    k_final<<<(N + 127) / 128, 256, 0, stream>>>(hid, h2l, pl, h2g, pg, N);
}

// Round 3
// 1315.784 us; speedup vs baseline: 1.8620x; 1.1565x over previous
//
#include <hip/hip_runtime.h>
#include <stdint.h>

#define F_IN 512
#define HDIM 128
#define CDIM 16
#define KHOPS 10

typedef __bf16 bf16x8 __attribute__((ext_vector_type(8)));
typedef float f32x4 __attribute__((ext_vector_type(4)));

typedef __attribute__((address_space(3))) unsigned int lds_uint;
typedef const __attribute__((address_space(1))) unsigned int g_uint;

__device__ __forceinline__ void dma16(const void* g, void* l) {
    __builtin_amdgcn_global_load_lds((g_uint*)g, (lds_uint*)l, 16, 0, 0);
}

__device__ __forceinline__ unsigned short f2bf(float f) {
    unsigned int u = __float_as_uint(f);
    u += 0x7FFFu + ((u >> 16) & 1u);
    return (unsigned short)(u >> 16);
}

__device__ __forceinline__ bf16x8 ld_bf8(const unsigned short* p) {
    uint4 u = *reinterpret_cast<const uint4*>(p);
    return __builtin_bit_cast(bf16x8, u);
}

// ---------------- CSC build ----------------

__global__ void k_count(const int* __restrict__ eidx, int* __restrict__ cnt, int E) {
    int e = blockIdx.x * 256 + threadIdx.x;
    if (e < E) atomicAdd(&cnt[eidx[E + e]], 1);
}

__global__ void k_dis(const int* __restrict__ cnt, float* __restrict__ dis, int N) {
    int v = blockIdx.x * 256 + threadIdx.x;
    if (v < N) dis[v] = rsqrtf((float)(cnt[v] + 1));
}

__global__ void k_scan1(const int* __restrict__ cnt, int* __restrict__ offs,
                        int* __restrict__ partials, int N) {
    __shared__ int sh[256];
    int t = threadIdx.x;
    int base = blockIdx.x * 1024 + t * 4;
    int v0 = (base + 0 < N) ? cnt[base + 0] : 0;
    int v1 = (base + 1 < N) ? cnt[base + 1] : 0;
    int v2 = (base + 2 < N) ? cnt[base + 2] : 0;
    int v3 = (base + 3 < N) ? cnt[base + 3] : 0;
    int s = v0 + v1 + v2 + v3;
    sh[t] = s;
    __syncthreads();
    for (int d = 1; d < 256; d <<= 1) {
        int x = (t >= d) ? sh[t - d] : 0;
        __syncthreads();
        sh[t] += x;
        __syncthreads();
    }
    int excl = sh[t] - s;
    if (base + 0 < N) offs[base + 0] = excl;
    excl += v0;
    if (base + 1 < N) offs[base + 1] = excl;
    excl += v1;
    if (base + 2 < N) offs[base + 2] = excl;
    excl += v2;
    if (base + 3 < N) offs[base + 3] = excl;
    if (t == 255) partials[blockIdx.x] = sh[255];
}

__global__ void k_scan2(int* __restrict__ partials, int nblk) {
    __shared__ int sh[256];
    int t = threadIdx.x;
    int i0 = t * 4;
    int v0 = (i0 + 0 < nblk) ? partials[i0 + 0] : 0;
    int v1 = (i0 + 1 < nblk) ? partials[i0 + 1] : 0;
    int v2 = (i0 + 2 < nblk) ? partials[i0 + 2] : 0;
    int v3 = (i0 + 3 < nblk) ? partials[i0 + 3] : 0;
    int s = v0 + v1 + v2 + v3;
    sh[t] = s;
    __syncthreads();
    for (int d = 1; d < 256; d <<= 1) {
        int x = (t >= d) ? sh[t - d] : 0;
        __syncthreads();
        sh[t] += x;
        __syncthreads();
    }
    int excl = sh[t] - s;
    if (i0 + 0 < nblk) partials[i0 + 0] = excl;
    excl += v0;
    if (i0 + 1 < nblk) partials[i0 + 1] = excl;
    excl += v1;
    if (i0 + 2 < nblk) partials[i0 + 2] = excl;
    excl += v2;
    if (i0 + 3 < nblk) partials[i0 + 3] = excl;
}

__global__ void k_scan3(int* __restrict__ offs, const int* __restrict__ partials, int N) {
    int i = blockIdx.x * 256 + threadIdx.x;
    if (i < N) offs[i] += partials[i >> 10];
}

__global__ void k_bucket(const int* __restrict__ eidx, const float* __restrict__ dis,
                         const int* __restrict__ offs, int* __restrict__ cursor,
                         uint2* __restrict__ srcnrm, int E) {
    int e = blockIdx.x * 256 + threadIdx.x;
    if (e >= E) return;
    int r = eidx[e];
    int c = eidx[E + e];
    int pos = offs[c] + atomicAdd(&cursor[c], 1);
    uint2 u;
    u.x = (unsigned)r;
    u.y = __float_as_uint(dis[r] * dis[c]);
    srcnrm[pos] = u;
}

// ---------------- x f32 -> bf16 (once) ----------------

__global__ void k_xbf(const float* __restrict__ x, unsigned short* __restrict__ xbf) {
    size_t i = (size_t)blockIdx.x * 2048 + (size_t)threadIdx.x * 8;
    float4 a = *reinterpret_cast<const float4*>(&x[i]);
    float4 b = *reinterpret_cast<const float4*>(&x[i + 4]);
    unsigned short s[8];
    s[0] = f2bf(a.x); s[1] = f2bf(a.y); s[2] = f2bf(a.z); s[3] = f2bf(a.w);
    s[4] = f2bf(b.x); s[5] = f2bf(b.y); s[6] = f2bf(b.z); s[7] = f2bf(b.w);
    *reinterpret_cast<uint4*>(&xbf[i]) = *reinterpret_cast<uint4*>(s);
}

// ---------------- W1 transpose+convert: [512][128] f32 -> [128][512] bf16 ----------------

__global__ void k_w1t(const float* __restrict__ W1l, const float* __restrict__ W1g,
                      unsigned short* __restrict__ W1Tl, unsigned short* __restrict__ W1Tg) {
    const float* W1 = blockIdx.y ? W1g : W1l;
    unsigned short* W1T = blockIdx.y ? W1Tg : W1Tl;
    int idx = blockIdx.x * 256 + threadIdx.x;
    int n = idx >> 6;
    int k0 = (idx & 63) * 8;
    unsigned short tmp[8];
    for (int j = 0; j < 8; j++)
        tmp[j] = f2bf(W1[(size_t)(k0 + j) * HDIM + n]);
    *reinterpret_cast<uint4*>(&W1T[(size_t)n * F_IN + k0]) = *reinterpret_cast<uint4*>(tmp);
}

// ---------------- fused GEMM: h1 = relu(x@W1+b1); h2 = h1@W2+b2 ----------------
// grid (ceil(N/128), 2), 256 threads. blockIdx.y = branch.
// LDS 34816 B union: K-loop { As 16K swizzled | Bs 16K swizzled } ; epilogue Hs [128][136] bf16.
// Swizzle: 16B-slot (row, cb) stored at slot row*8 + (cb ^ (row&7)). global_load_lds writes
// contiguous slots (wave-uniform base + lane*16), global addr per-lane decodes the swizzle.

__global__ __launch_bounds__(256, 4) void k_gemm(
    const unsigned short* __restrict__ xbf,
    const unsigned short* __restrict__ W1Tl, const float* __restrict__ b1l,
    const float* __restrict__ W2l, const float* __restrict__ b2l, const float* __restrict__ tl,
    const unsigned short* __restrict__ W1Tg, const float* __restrict__ b1g,
    const float* __restrict__ W2g, const float* __restrict__ b2g, const float* __restrict__ tg,
    float* __restrict__ h1l, float* __restrict__ h1g,
    float* __restrict__ xc0, float* __restrict__ hid, int nNode)
{
    const int br = blockIdx.y;
    const unsigned short* w1t = br ? W1Tg : W1Tl;
    const float* B1 = br ? b1g : b1l;
    const float* W2 = br ? W2g : W2l;
    const float* B2 = br ? b2g : b2l;
    const float* tp = br ? tg : tl;
    float* h1 = br ? h1g : h1l;

    __shared__ __align__(16) unsigned short sm[17408];   // 34816 B
    unsigned short* As = sm;            // slots 0..1023   (rows 0..127 x 8 slots)
    unsigned short* Bs = sm + 8192;     // slots 0..1023
    unsigned short* Hs = sm;            // [128][136] epilogue

    const int t = threadIdx.x;
    const int lane = t & 63;
    const int w = t >> 6;
    const int row0 = blockIdx.x * 128;

    f32x4 acc[2][8];
    for (int i = 0; i < 2; i++)
        for (int j = 0; j < 8; j++)
            acc[i][j] = f32x4{0.f, 0.f, 0.f, 0.f};

    const int m16 = lane & 15;
    const int q = lane >> 4;

    for (int k0 = 0; k0 < F_IN; k0 += 64) {
        // stage A (rows of x) + B (n-rows of W1T): 4+4 DMA insts per wave
        #pragma unroll
        for (int j = 0; j < 4; j++) {
            int S0 = w * 256 + j * 64;
            int S = S0 + lane;
            int row = S >> 3;
            int cb = (S & 7) ^ (row & 7);
            dma16(&xbf[(size_t)(row0 + row) * F_IN + k0 + cb * 8], &As[(size_t)S0 * 8]);
        }
        #pragma unroll
        for (int j = 0; j < 4; j++) {
            int S0 = w * 256 + j * 64;
            int S = S0 + lane;
            int n = S >> 3;
            int cb = (S & 7) ^ (n & 7);
            dma16(&w1t[(size_t)n * F_IN + k0 + cb * 8], &Bs[(size_t)S0 * 8]);
        }
        __syncthreads();

        #pragma unroll
        for (int ksub = 0; ksub < 2; ksub++) {
            bf16x8 bf[8];
            #pragma unroll
            for (int ns = 0; ns < 8; ns++) {
                int n = ns * 16 + m16;
                int slot = n * 8 + ((ksub * 4 + q) ^ (n & 7));
                bf[ns] = ld_bf8(&Bs[slot * 8]);
            }
            bf16x8 af[2];
            #pragma unroll
            for (int ms = 0; ms < 2; ms++) {
                int row = w * 32 + ms * 16 + m16;
                int slot = row * 8 + ((ksub * 4 + q) ^ (row & 7));
                af[ms] = ld_bf8(&As[slot * 8]);
            }
            #pragma unroll
            for (int ns = 0; ns < 8; ns++)
                #pragma unroll
                for (int ms = 0; ms < 2; ms++)
                    acc[ms][ns] = __builtin_amdgcn_mfma_f32_16x16x32_bf16(af[ms], bf[ns], acc[ms][ns], 0, 0, 0);
        }
        __syncthreads();
    }

    // epilogue 1: h1 = relu(acc + b1); write global + stash bf16 in LDS
    #pragma unroll
    for (int ms = 0; ms < 2; ms++) {
        #pragma unroll
        for (int ns = 0; ns < 8; ns++) {
            int n = ns * 16 + m16;
            float bias = B1[n];
            #pragma unroll
            for (int r = 0; r < 4; r++) {
                int m = w * 32 + ms * 16 + q * 4 + r;
                float v = acc[ms][ns][r] + bias;
                v = v > 0.f ? v : 0.f;
                Hs[m * 136 + n] = f2bf(v);
                int node = row0 + m;
                if (node < nNode) h1[(size_t)node * HDIM + n] = v;
            }
        }
    }
    __syncthreads();

    // epilogue 2: h2 = h1 @ W2 + b2 via MFMA (N=16). wave w does m-tiles 2w, 2w+1.
    {
        float t0 = tp[0];
        float bias = B2[m16];
        #pragma unroll
        for (int mi = 0; mi < 2; mi++) {
            int mt = w * 2 + mi;
            f32x4 acc2 = f32x4{bias, bias, bias, bias};
            #pragma unroll
            for (int kb = 0; kb < 4; kb++) {
                bf16x8 hf = ld_bf8(&Hs[(mt * 16 + m16) * 136 + kb * 32 + q * 8]);
                unsigned short wtmp[8];
                #pragma unroll
                for (int j = 0; j < 8; j++)
                    wtmp[j] = f2bf(W2[(size_t)(kb * 32 + q * 8 + j) * CDIM + m16]);
                bf16x8 wf = ld_bf8(wtmp);
                acc2 = __builtin_amdgcn_mfma_f32_16x16x32_bf16(hf, wf, acc2, 0, 0, 0);
            }
            #pragma unroll
            for (int r = 0; r < 4; r++) {
                int node = row0 + mt * 16 + q * 4 + r;
                if (node < nNode) {
                    size_t idx = (size_t)node * 32 + (size_t)br * 16 + m16;
                    xc0[idx] = acc2[r];
                    hid[idx] = t0 * acc2[r];
                }
            }
        }
    }
}

// ---------------- propagation hop: 8 lanes/node x float4 channels ----------------
// block 256 = 32 nodes; per gather inst a wave serves 8 full edge-gathers.

__global__ __launch_bounds__(256) void k_hop(
    const float* __restrict__ xin, float* __restrict__ xout,
    float* __restrict__ hid, const uint2* __restrict__ srcnrm,
    const int* __restrict__ offs, const int* __restrict__ cnt,
    const float* __restrict__ dis,
    const float* __restrict__ tl, const float* __restrict__ tg,
    int hop, int N)
{
    int t = threadIdx.x;
    int v = blockIdx.x * 32 + (t >> 3);
    int c4 = (t & 7) * 4;
    if (v >= N) return;
    int off = offs[v];
    int m = cnt[v];
    float d = dis[v];
    size_t vbase = (size_t)v * 32 + c4;
    float4 xv = *reinterpret_cast<const float4*>(xin + vbase);
    float dd = d * d;
    float4 acc = make_float4(dd * xv.x, dd * xv.y, dd * xv.z, dd * xv.w);
    const uint2* ep = srcnrm + off;
    int i = 0;
    for (; i + 8 <= m; i += 8) {
        uint2 u[8];
        #pragma unroll
        for (int j = 0; j < 8; j++) u[j] = ep[i + j];
        float4 xs[8];
        #pragma unroll
        for (int j = 0; j < 8; j++)
            xs[j] = *reinterpret_cast<const float4*>(xin + (size_t)u[j].x * 32 + c4);
        #pragma unroll
        for (int j = 0; j < 8; j++) {
            float nrm = __uint_as_float(u[j].y);
            acc.x = fmaf(nrm, xs[j].x, acc.x);
            acc.y = fmaf(nrm, xs[j].y, acc.y);
            acc.z = fmaf(nrm, xs[j].z, acc.z);
            acc.w = fmaf(nrm, xs[j].w, acc.w);
        }
    }
    for (; i < m; i++) {
        uint2 u = ep[i];
        float nrm = __uint_as_float(u.y);
        float4 xs = *reinterpret_cast<const float4*>(xin + (size_t)u.x * 32 + c4);
        acc.x = fmaf(nrm, xs.x, acc.x);
        acc.y = fmaf(nrm, xs.y, acc.y);
        acc.z = fmaf(nrm, xs.z, acc.z);
        acc.w = fmaf(nrm, xs.w, acc.w);
    }
    *reinterpret_cast<float4*>(xout + vbase) = acc;
    float gamma = (c4 < 16 ? tl : tg)[hop];
    float4 h = *reinterpret_cast<const float4*>(hid + vbase);
    h.x = fmaf(gamma, acc.x, h.x);
    h.y = fmaf(gamma, acc.y, h.y);
    h.z = fmaf(gamma, acc.z, h.z);
    h.w = fmaf(gamma, acc.w, h.w);
    *reinterpret_cast<float4*>(hid + vbase) = h;
}

// ---------------- final: split hid, log_softmax ----------------

__global__ void k_final(const float* __restrict__ hid,
                        float* __restrict__ h2l, float* __restrict__ pl,
                        float* __restrict__ h2g, float* __restrict__ pg, int N)
{
    int t = threadIdx.x;
    int v = blockIdx.x * 128 + (t >> 1);
    int br = t & 1;
    if (v >= N) return;
    float xv[16];
    const float* src = &hid[(size_t)v * 32 + (size_t)br * 16];
    for (int j = 0; j < 16; j += 4)
        *reinterpret_cast<float4*>(&xv[j]) = *reinterpret_cast<const float4*>(&src[j]);
    float mx = xv[0];
    for (int j = 1; j < 16; j++) mx = fmaxf(mx, xv[j]);
    float s = 0.f;
    for (int j = 0; j < 16; j++) s += __expf(xv[j] - mx);
    float lse = mx + __logf(s);
    float* h2 = br ? h2g : h2l;
    float* pp = br ? pg : pl;
    for (int j = 0; j < 16; j++) {
        h2[(size_t)v * 16 + j] = xv[j];
        pp[(size_t)v * 16 + j] = xv[j] - lse;
    }
}

// ---------------- launch ----------------

extern "C" void kernel_launch(void* const* d_in, const int* in_sizes, int n_in,
                              void* d_out, int out_size, void* d_ws, size_t ws_size,
                              hipStream_t stream)
{
    const float* x   = (const float*)d_in[0];
    const int*   eidx= (const int*)d_in[1];
    const float* W1l = (const float*)d_in[2];
    const float* b1l = (const float*)d_in[3];
    const float* W2l = (const float*)d_in[4];
    const float* b2l = (const float*)d_in[5];
    const float* tl  = (const float*)d_in[6];
    const float* W1g = (const float*)d_in[7];
    const float* b1g = (const float*)d_in[8];
    const float* W2g = (const float*)d_in[9];
    const float* b2g = (const float*)d_in[10];
    const float* tg  = (const float*)d_in[11];

    const int N = in_sizes[0] / F_IN;
    const int E = in_sizes[1] / 2;

    float* out = (float*)d_out;
    float* h1l = out;
    float* h2l = h1l + (size_t)N * HDIM;
    float* pl  = h2l + (size_t)N * CDIM;
    float* h1g = pl  + (size_t)N * CDIM;
    float* h2g = h1g + (size_t)N * HDIM;
    float* pg  = h2g + (size_t)N * CDIM;

    char* ws = (char*)d_ws;
    auto alloc = [&](size_t bytes) -> char* {
        char* p = ws;
        ws += (bytes + 1023) & ~(size_t)1023;
        return p;
    };
    int*   cnt      = (int*)alloc((size_t)N * 4);
    int*   offs     = (int*)alloc((size_t)N * 4);
    int*   cursor   = (int*)alloc((size_t)N * 4);
    float* dis      = (float*)alloc((size_t)N * 4);
    int*   partials = (int*)alloc(4096);
    uint2* srcnrm   = (uint2*)alloc((size_t)E * 8);
    float* xcA      = (float*)alloc((size_t)N * 32 * 4);
    float* xcB      = (float*)alloc((size_t)N * 32 * 4);
    float* hid      = (float*)alloc((size_t)N * 32 * 4);
    unsigned short* W1Tl = (unsigned short*)alloc((size_t)HDIM * F_IN * 2);
    unsigned short* W1Tg = (unsigned short*)alloc((size_t)HDIM * F_IN * 2);
    unsigned short* xbf  = (unsigned short*)alloc((size_t)(N + 256) * F_IN * 2);

    hipMemsetAsync(cnt, 0, (size_t)N * 4, stream);
    hipMemsetAsync(cursor, 0, (size_t)N * 4, stream);

    int gE = (E + 255) / 256;
    int gN = (N + 255) / 256;
    int nblk = (N + 1023) / 1024;

    k_count<<<gE, 256, 0, stream>>>(eidx, cnt, E);
    k_dis<<<gN, 256, 0, stream>>>(cnt, dis, N);
    k_scan1<<<nblk, 256, 0, stream>>>(cnt, offs, partials, N);
    k_scan2<<<1, 256, 0, stream>>>(partials, nblk);
    k_scan3<<<gN, 256, 0, stream>>>(offs, partials, N);
    k_bucket<<<gE, 256, 0, stream>>>(eidx, dis, offs, cursor, srcnrm, E);

    k_xbf<<<(int)(((size_t)N * F_IN) / 2048), 256, 0, stream>>>(x, xbf);
    dim3 gw(32, 2);
    k_w1t<<<gw, 256, 0, stream>>>(W1l, W1g, W1Tl, W1Tg);

    dim3 gg((N + 127) / 128, 2);
    k_gemm<<<gg, 256, 0, stream>>>(xbf, W1Tl, b1l, W2l, b2l, tl,
                                   W1Tg, b1g, W2g, b2g, tg,
                                   h1l, h1g, xcA, hid, N);

    int gh = (N + 31) / 32;
    float* a = xcA;
    float* b = xcB;
    for (int k = 1; k <= KHOPS; k++) {
        k_hop<<<gh, 256, 0, stream>>>(a, b, hid, srcnrm, offs, cnt, dis, tl, tg, k, N);
        float* tmp = a; a = b; b = tmp;
    }
    k_final<<<(N + 127) / 128, 256, 0, stream>>>(hid, h2l, pl, h2g, pg, N);
}